// Round 2
// baseline (153.453 us; speedup 1.0000x reference)
//
#include <hip/hip_runtime.h>
#include <hip/hip_bf16.h>

#define BSZ  16
#define NTOK 128
#define CHN  512
#define KTOT 1024
#define EPSV 1e-5f

// LDS staging geometry: 4 quarters x 32 channels x 132-padded columns
#define LROW 132
#define QS   (32 * LROW)   // 4224 floats, 4224 % 32 == 0 -> quarter offset bank-neutral

typedef __attribute__((ext_vector_type(8))) short bf16x8;
typedef __attribute__((ext_vector_type(4))) float f32x4;

union BfPack4 { ushort4 u; __hip_bfloat16 h[4]; };

// ---------------------------------------------------------------------------
// K1: block = (batch b, rows i0..i0+3), 512 threads (8 waves, 16 waves/CU).
//  phase 0: convert one Wf row (row = blockIdx.x) to bf16
//  phase 1: scores, 4-way channel split (j = t&127 owns column, q = t>>7 owns
//           128 channels), LDS-staged transposed x tiles (bank-conflict-free)
//  softmax: shift-invariant (only BN scale + diagonal matter), 2 waves
//  phase 2: xnb = W @ x[b], 4-way j-split + LDS partial reduce (overlaid on
//           the staging buffer), write bf16 [x | xnb]
// ---------------------------------------------------------------------------
__global__ __launch_bounds__(512, 4)
void k1_score_softmax_xnb(const float* __restrict__ xg,
                          const float* __restrict__ wde,     // conv_e_w[:512]
                          const float* __restrict__ bn_e_g,
                          const float* __restrict__ bn_e_v,
                          const float* __restrict__ wf,      // conv_f_w [512][1024]
                          __hip_bfloat16* __restrict__ hb,   // [2048][1024]
                          __hip_bfloat16* __restrict__ wfb)  // [512][1024]
{
    __shared__ float smem[4 * QS];        // phase1: xs[q][c][j] ; phase2: part2[4][4][512]
    __shared__ float part[4][4][128];     // phase1 cross-quarter partials
    __shared__ float wrow[4][LROW];       // softmax weights
    __shared__ float red[16];             // cross-wave softmax reduction

    const int t   = threadIdx.x;
    const int blk = blockIdx.x;
    const int b   = blk >> 5;
    const int i0  = (blk & 31) << 2;
    const float* __restrict__ xb = xg + (size_t)b * NTOK * CHN;

    // ---- phase 0: Wf row blk -> bf16 ----
    if (t < 256) {
        const float* wr = wf + (size_t)blk * KTOT;
        float4 u = *(const float4*)&wr[t * 4];
        BfPack4 p;
        p.h[0] = __float2bfloat16(u.x); p.h[1] = __float2bfloat16(u.y);
        p.h[2] = __float2bfloat16(u.z); p.h[3] = __float2bfloat16(u.w);
        *(ushort4*)&wfb[(size_t)blk * KTOT + t * 4] = p.u;
    }

    // ---- phase 1: thread (j = t&127, q = t>>7) accumulates 128 channels ----
    const int j = t & 127;
    const int q = t >> 7;
    float acc[4] = {0.f, 0.f, 0.f, 0.f};

    const int j_s = t >> 2;      // staging: 4 threads per j-row
    const int lg  = t & 3;

    for (int s = 0; s < 4; ++s) {
        // stage channels {qq*128 + s*32 .. +32} for all qq, transposed
        #pragma unroll
        for (int g = 0; g < 8; ++g) {
            const int G   = lg + 4 * g;          // 0..31 float4-groups
            const int qq  = G >> 3;
            const int idx = G & 7;
            const int cg  = qq * 128 + s * 32 + idx * 4;
            float4 v = *(const float4*)&xb[(size_t)j_s * CHN + cg];
            float* dst = &smem[qq * QS + (idx * 4) * LROW + j_s];
            dst[0 * LROW] = v.x; dst[1 * LROW] = v.y;
            dst[2 * LROW] = v.z; dst[3 * LROW] = v.w;
        }
        __syncthreads();

        const int cbase = q * 128 + s * 32;
        #pragma unroll
        for (int g = 0; g < 8; ++g) {
            const int c = cbase + g * 4;
            const float4 wd  = *(const float4*)&wde[c];                          // uniform
            const float4 xi0 = *(const float4*)&xb[(size_t)(i0 + 0) * CHN + c];  // uniform
            const float4 xi1 = *(const float4*)&xb[(size_t)(i0 + 1) * CHN + c];
            const float4 xi2 = *(const float4*)&xb[(size_t)(i0 + 2) * CHN + c];
            const float4 xi3 = *(const float4*)&xb[(size_t)(i0 + 3) * CHN + c];
            const float* xr = &smem[q * QS + (g * 4) * LROW + j];
            const float xj0 = xr[0 * LROW];
            const float xj1 = xr[1 * LROW];
            const float xj2 = xr[2 * LROW];
            const float xj3 = xr[3 * LROW];
            acc[0] += fabsf(xi0.x - xj0) * wd.x + fabsf(xi0.y - xj1) * wd.y
                    + fabsf(xi0.z - xj2) * wd.z + fabsf(xi0.w - xj3) * wd.w;
            acc[1] += fabsf(xi1.x - xj0) * wd.x + fabsf(xi1.y - xj1) * wd.y
                    + fabsf(xi1.z - xj2) * wd.z + fabsf(xi1.w - xj3) * wd.w;
            acc[2] += fabsf(xi2.x - xj0) * wd.x + fabsf(xi2.y - xj1) * wd.y
                    + fabsf(xi2.z - xj2) * wd.z + fabsf(xi2.w - xj3) * wd.w;
            acc[3] += fabsf(xi3.x - xj0) * wd.x + fabsf(xi3.y - xj1) * wd.y
                    + fabsf(xi3.z - xj2) * wd.z + fabsf(xi3.w - xj3) * wd.w;
        }
        __syncthreads();
    }

    // cross-quarter reduce
    #pragma unroll
    for (int ti = 0; ti < 4; ++ti) part[q][ti][j] = acc[ti];
    __syncthreads();

    // ---- softmax over j (threads 0..127 = 2 full waves) ----
    if (t < 128) {
        const float sc = bn_e_g[0] * rsqrtf(bn_e_v[0] + EPSV);
        float logit[4];
        #pragma unroll
        for (int ti = 0; ti < 4; ++ti) {
            logit[ti] = (part[0][ti][t] + part[1][ti][t]
                       + part[2][ti][t] + part[3][ti][t]) * sc;
            if (t == i0 + ti) logit[ti] -= 1e8f;   // diagonal mask
        }
        const int wid = t >> 6, lane = t & 63;
        float mx[4];
        #pragma unroll
        for (int ti = 0; ti < 4; ++ti) {
            float v = logit[ti];
            #pragma unroll
            for (int off = 32; off > 0; off >>= 1) v = fmaxf(v, __shfl_xor(v, off));
            mx[ti] = v;
        }
        if (lane == 0) {
            red[wid * 8 + 0] = mx[0]; red[wid * 8 + 1] = mx[1];
            red[wid * 8 + 2] = mx[2]; red[wid * 8 + 3] = mx[3];
        }
        __syncthreads();
        float pe[4], sm[4];
        #pragma unroll
        for (int ti = 0; ti < 4; ++ti) {
            const float M = fmaxf(red[ti], red[8 + ti]);
            pe[ti] = __expf(logit[ti] - M);
            float v = pe[ti];
            #pragma unroll
            for (int off = 32; off > 0; off >>= 1) v += __shfl_xor(v, off);
            sm[ti] = v;
        }
        if (lane == 0) {
            red[wid * 8 + 4] = sm[0]; red[wid * 8 + 5] = sm[1];
            red[wid * 8 + 6] = sm[2]; red[wid * 8 + 7] = sm[3];
        }
        __syncthreads();
        #pragma unroll
        for (int ti = 0; ti < 4; ++ti) {
            const float S = red[4 + ti] + red[12 + ti];
            wrow[ti][t] = pe[ti] / S;
        }
    } else {
        __syncthreads();  // match the two syncs inside the if-branch
        __syncthreads();
    }
    __syncthreads();

    // ---- phase 2: xnb = W @ x[b], 4-way j-split, partials in smem overlay ----
    const int c4 = (t & 127) << 2;
    const int jq = t >> 7;
    float4 a2[4];
    #pragma unroll
    for (int ti = 0; ti < 4; ++ti) { a2[ti].x = a2[ti].y = a2[ti].z = a2[ti].w = 0.f; }

    #pragma unroll 4
    for (int jj = 0; jj < 32; ++jj) {
        const int jx = jq * 32 + jj;
        const float4 xj = *(const float4*)&xb[(size_t)jx * CHN + c4];
        const float w0 = wrow[0][jx], w1 = wrow[1][jx];
        const float w2 = wrow[2][jx], w3 = wrow[3][jx];
        a2[0].x += w0 * xj.x; a2[0].y += w0 * xj.y; a2[0].z += w0 * xj.z; a2[0].w += w0 * xj.w;
        a2[1].x += w1 * xj.x; a2[1].y += w1 * xj.y; a2[1].z += w1 * xj.z; a2[1].w += w1 * xj.w;
        a2[2].x += w2 * xj.x; a2[2].y += w2 * xj.y; a2[2].z += w2 * xj.z; a2[2].w += w2 * xj.w;
        a2[3].x += w3 * xj.x; a2[3].y += w3 * xj.y; a2[3].z += w3 * xj.z; a2[3].w += w3 * xj.w;
    }
    #pragma unroll
    for (int ti = 0; ti < 4; ++ti)
        *(float4*)&smem[(jq * 4 + ti) * CHN + c4] = a2[ti];
    __syncthreads();

    // final sum + bf16 write of [x | xnb]; thread owns (row ti2, channels c4..c4+3)
    {
        const int ti2 = t >> 7;
        float4 s0 = *(const float4*)&smem[(0 * 4 + ti2) * CHN + c4];
        float4 s1 = *(const float4*)&smem[(1 * 4 + ti2) * CHN + c4];
        float4 s2 = *(const float4*)&smem[(2 * 4 + ti2) * CHN + c4];
        float4 s3 = *(const float4*)&smem[(3 * 4 + ti2) * CHN + c4];
        float4 sum;
        sum.x = s0.x + s1.x + s2.x + s3.x;
        sum.y = s0.y + s1.y + s2.y + s3.y;
        sum.z = s0.z + s1.z + s2.z + s3.z;
        sum.w = s0.w + s1.w + s2.w + s3.w;
        const size_t row = (size_t)(b * NTOK + i0 + ti2);
        BfPack4 pk;
        pk.h[0] = __float2bfloat16(sum.x); pk.h[1] = __float2bfloat16(sum.y);
        pk.h[2] = __float2bfloat16(sum.z); pk.h[3] = __float2bfloat16(sum.w);
        *(ushort4*)&hb[row * KTOT + CHN + c4] = pk.u;
        const float4 xv = *(const float4*)&xb[(size_t)(i0 + ti2) * CHN + c4];
        pk.h[0] = __float2bfloat16(xv.x); pk.h[1] = __float2bfloat16(xv.y);
        pk.h[2] = __float2bfloat16(xv.z); pk.h[3] = __float2bfloat16(xv.w);
        *(ushort4*)&hb[row * KTOT + c4] = pk.u;
    }
}

// ---------------------------------------------------------------------------
// K2: out = relu(BN([x|xnb] @ Wf^T + bias)) via bf16 MFMA, direct global frags.
// 256 blocks (32 row-tiles x 8 col-tiles of 64x64), 4 waves of 2x2 16x16 tiles.
// ---------------------------------------------------------------------------
__global__ __launch_bounds__(256)
void k2_gemm_bn_relu(const __hip_bfloat16* __restrict__ hbp,
                     const __hip_bfloat16* __restrict__ wfbp,
                     const float* __restrict__ fb,
                     const float* __restrict__ gg,
                     const float* __restrict__ bb,
                     const float* __restrict__ mm,
                     const float* __restrict__ vv,
                     float* __restrict__ out)
{
    const int blk  = blockIdx.x;
    const int r0   = (blk >> 3) << 6;
    const int c0   = (blk & 7) << 6;
    const int t    = threadIdx.x;
    const int w    = t >> 6;
    const int lane = t & 63;
    const int wm   = w & 1;
    const int wn   = w >> 1;
    const int m16  = lane & 15;
    const int qq   = lane >> 4;

    const short* A0 = (const short*)hbp  + (size_t)(r0 + wm * 32 + m16) * KTOT + qq * 8;
    const short* B0 = (const short*)wfbp + (size_t)(c0 + wn * 32 + m16) * KTOT + qq * 8;

    f32x4 acc00 = {0.f, 0.f, 0.f, 0.f};
    f32x4 acc01 = acc00, acc10 = acc00, acc11 = acc00;

    #pragma unroll 4
    for (int k0 = 0; k0 < KTOT; k0 += 32) {
        const bf16x8 aA = *(const bf16x8*)(A0 + k0);
        const bf16x8 aB = *(const bf16x8*)(A0 + 16 * KTOT + k0);
        const bf16x8 bA = *(const bf16x8*)(B0 + k0);
        const bf16x8 bB = *(const bf16x8*)(B0 + 16 * KTOT + k0);
        acc00 = __builtin_amdgcn_mfma_f32_16x16x32_bf16(aA, bA, acc00, 0, 0, 0);
        acc01 = __builtin_amdgcn_mfma_f32_16x16x32_bf16(aA, bB, acc01, 0, 0, 0);
        acc10 = __builtin_amdgcn_mfma_f32_16x16x32_bf16(aB, bA, acc10, 0, 0, 0);
        acc11 = __builtin_amdgcn_mfma_f32_16x16x32_bf16(aB, bB, acc11, 0, 0, 0);
    }

    // epilogue: C/D layout col = lane&15, row = (lane>>4)*4 + reg  [m89-verified]
    #pragma unroll
    for (int ni = 0; ni < 2; ++ni) {
        const int c = c0 + wn * 32 + ni * 16 + m16;
        const float gf = gg[c] * rsqrtf(vv[c] + EPSV);
        const float ad = fb[c] - mm[c];
        const float bv = bb[c];
        const f32x4 acr0 = ni ? acc01 : acc00;
        const f32x4 acr1 = ni ? acc11 : acc10;
        #pragma unroll
        for (int r2 = 0; r2 < 4; ++r2) {
            int row = r0 + wm * 32 + qq * 4 + r2;
            float val = (acr0[r2] + ad) * gf + bv;
            out[(size_t)row * CHN + c] = fmaxf(val, 0.f);
            row += 16;
            val = (acr1[r2] + ad) * gf + bv;
            out[(size_t)row * CHN + c] = fmaxf(val, 0.f);
        }
    }
}

extern "C" void kernel_launch(void* const* d_in, const int* in_sizes, int n_in,
                              void* d_out, int out_size, void* d_ws, size_t ws_size,
                              hipStream_t stream) {
    const float* x        = (const float*)d_in[0];
    // d_in[1] = y          : unused (softmax shift-invariance)
    const float* conv_e_w = (const float*)d_in[2];
    // d_in[3] = conv_e_b   : unused (shift)
    const float* bn_e_g   = (const float*)d_in[4];
    // d_in[5] = bn_e_b     : unused (shift)
    // d_in[6] = bn_e_m     : unused (shift)
    const float* bn_e_v   = (const float*)d_in[7];
    const float* conv_f_w = (const float*)d_in[8];
    const float* conv_f_b = (const float*)d_in[9];
    const float* bn_f_g   = (const float*)d_in[10];
    const float* bn_f_b   = (const float*)d_in[11];
    const float* bn_f_m   = (const float*)d_in[12];
    const float* bn_f_v   = (const float*)d_in[13];
    float* out = (float*)d_out;

    __hip_bfloat16* hb  = (__hip_bfloat16*)d_ws;              // 2048*1024 bf16 = 4 MB
    __hip_bfloat16* wfb = hb + (size_t)2048 * 1024;           // 512*1024 bf16  = 1 MB

    k1_score_softmax_xnb<<<512, 512, 0, stream>>>(x, conv_e_w, bn_e_g, bn_e_v,
                                                  conv_f_w, hb, wfb);
    k2_gemm_bn_relu<<<256, 256, 0, stream>>>(hb, wfb, conv_f_b, bn_f_g, bn_f_b,
                                             bn_f_m, bn_f_v, out);
}

// Round 3
// 131.911 us; speedup vs baseline: 1.1633x; 1.1633x over previous
//
#include <hip/hip_runtime.h>
#include <hip/hip_bf16.h>

#define NTOK 128
#define CHN  512
#define KTOT 1024
#define EPSV 1e-5f
#define LR1  129   // xs row stride in floats: bank(c,j) = (c + j) % 32 -> 2-way max (free)

typedef __attribute__((ext_vector_type(8))) short bf16x8;
typedef __attribute__((ext_vector_type(4))) float f32x4;

union BfPack4 { ushort4 u; __hip_bfloat16 h[4]; };

// ---------------------------------------------------------------------------
// K1: block = (batch b, rows i0..i0+3), 256 threads (4 waves).
//  phase 0: Wf row blk -> bf16
//  phase 1: scores. 2-way channel split (q = t>>7 owns 256 ch), 8 chunks of
//           64 ch staged transposed in LDS with stride-129 rows (conflict-free)
//  softmax: shift-invariant (only BN scale + diagonal matter), waves 0-1
//  phase 2: xnb = W @ x[b], 2-way j-split, partials overlaid on xs, then
//           reduce + bf16 write of [x | xnb]
// ---------------------------------------------------------------------------
__global__ __launch_bounds__(256, 3)
void k1_score_softmax_xnb(const float* __restrict__ xg,
                          const float* __restrict__ wde,     // conv_e_w[:512]
                          const float* __restrict__ bn_e_g,
                          const float* __restrict__ bn_e_v,
                          const float* __restrict__ wf,      // conv_f_w [512][1024]
                          __hip_bfloat16* __restrict__ hb,   // [2048][1024]
                          __hip_bfloat16* __restrict__ wfb)  // [512][1024]
{
    __shared__ float xs[64 * LR1];       // 33 KB; phase-2 overlay part2[2][4][512]
    __shared__ float part1[2][4][128];   // phase-1 cross-half partials
    __shared__ float wrow[4][128];       // softmax weights
    __shared__ float red[16];

    const int t   = threadIdx.x;
    const int blk = blockIdx.x;
    const int b   = blk >> 5;
    const int i0  = (blk & 31) << 2;
    const float* __restrict__ xb = xg + (size_t)b * NTOK * CHN;

    // ---- phase 0: Wf row blk -> bf16 (256 thr x 4 floats) ----
    {
        const float* wr = wf + (size_t)blk * KTOT;
        float4 u = *(const float4*)&wr[t * 4];
        BfPack4 p;
        p.h[0] = __float2bfloat16(u.x); p.h[1] = __float2bfloat16(u.y);
        p.h[2] = __float2bfloat16(u.z); p.h[3] = __float2bfloat16(u.w);
        *(ushort4*)&wfb[(size_t)blk * KTOT + t * 4] = p.u;
    }

    // ---- phase 1 ----
    const int j = t & 127;                                   // owned column
    const int q = __builtin_amdgcn_readfirstlane(t >> 7);    // channel half (wave-uniform)
    float acc[4] = {0.f, 0.f, 0.f, 0.f};

    const int cl_s = (t & 15) * 4;   // staging: channel group
    const int j0_s = t >> 4;         // staging: row base

    for (int s = 0; s < 8; ++s) {
        const int cs = s * 64;
        // stage x[b][all j][cs..cs+63] transposed -> xs[c][j], 2-way banks
        #pragma unroll
        for (int u = 0; u < 8; ++u) {
            const int jj = j0_s + 16 * u;
            float4 v = *(const float4*)&xb[(size_t)jj * CHN + cs + cl_s];
            xs[(cl_s + 0) * LR1 + jj] = v.x;
            xs[(cl_s + 1) * LR1 + jj] = v.y;
            xs[(cl_s + 2) * LR1 + jj] = v.z;
            xs[(cl_s + 3) * LR1 + jj] = v.w;
        }
        __syncthreads();

        const int cb = cs + q * 32;
        #pragma unroll
        for (int g = 0; g < 8; ++g) {
            const int c = cb + g * 4;
            const float4 wd  = *(const float4*)&wde[c];                          // scalar
            const float4 xi0 = *(const float4*)&xb[(size_t)(i0 + 0) * CHN + c];  // scalar
            const float4 xi1 = *(const float4*)&xb[(size_t)(i0 + 1) * CHN + c];
            const float4 xi2 = *(const float4*)&xb[(size_t)(i0 + 2) * CHN + c];
            const float4 xi3 = *(const float4*)&xb[(size_t)(i0 + 3) * CHN + c];
            const float* xr = &xs[(q * 32 + g * 4) * LR1 + j];
            const float xj0 = xr[0 * LR1];
            const float xj1 = xr[1 * LR1];
            const float xj2 = xr[2 * LR1];
            const float xj3 = xr[3 * LR1];
            acc[0] += fabsf(xi0.x - xj0) * wd.x + fabsf(xi0.y - xj1) * wd.y
                    + fabsf(xi0.z - xj2) * wd.z + fabsf(xi0.w - xj3) * wd.w;
            acc[1] += fabsf(xi1.x - xj0) * wd.x + fabsf(xi1.y - xj1) * wd.y
                    + fabsf(xi1.z - xj2) * wd.z + fabsf(xi1.w - xj3) * wd.w;
            acc[2] += fabsf(xi2.x - xj0) * wd.x + fabsf(xi2.y - xj1) * wd.y
                    + fabsf(xi2.z - xj2) * wd.z + fabsf(xi2.w - xj3) * wd.w;
            acc[3] += fabsf(xi3.x - xj0) * wd.x + fabsf(xi3.y - xj1) * wd.y
                    + fabsf(xi3.z - xj2) * wd.z + fabsf(xi3.w - xj3) * wd.w;
        }
        __syncthreads();
    }

    part1[q][0][j] = acc[0];
    part1[q][1][j] = acc[1];
    part1[q][2][j] = acc[2];
    part1[q][3][j] = acc[3];
    __syncthreads();

    // ---- softmax over j (waves 0-1) ----
    if (t < 128) {
        const float sc = bn_e_g[0] * rsqrtf(bn_e_v[0] + EPSV);
        float logit[4];
        #pragma unroll
        for (int ti = 0; ti < 4; ++ti) {
            logit[ti] = (part1[0][ti][t] + part1[1][ti][t]) * sc;
            if (t == i0 + ti) logit[ti] -= 1e8f;   // diagonal mask
        }
        const int wid = t >> 6, lane = t & 63;
        float mx[4];
        #pragma unroll
        for (int ti = 0; ti < 4; ++ti) {
            float v = logit[ti];
            #pragma unroll
            for (int off = 32; off > 0; off >>= 1) v = fmaxf(v, __shfl_xor(v, off));
            mx[ti] = v;
        }
        if (lane == 0) {
            red[wid * 8 + 0] = mx[0]; red[wid * 8 + 1] = mx[1];
            red[wid * 8 + 2] = mx[2]; red[wid * 8 + 3] = mx[3];
        }
        __syncthreads();
        float pe[4], sm[4];
        #pragma unroll
        for (int ti = 0; ti < 4; ++ti) {
            const float M = fmaxf(red[ti], red[8 + ti]);
            pe[ti] = __expf(logit[ti] - M);
            float v = pe[ti];
            #pragma unroll
            for (int off = 32; off > 0; off >>= 1) v += __shfl_xor(v, off);
            sm[ti] = v;
        }
        if (lane == 0) {
            red[wid * 8 + 4] = sm[0]; red[wid * 8 + 5] = sm[1];
            red[wid * 8 + 6] = sm[2]; red[wid * 8 + 7] = sm[3];
        }
        __syncthreads();
        #pragma unroll
        for (int ti = 0; ti < 4; ++ti) {
            const float S = red[4 + ti] + red[12 + ti];
            wrow[ti][t] = pe[ti] / S;
        }
    } else {
        __syncthreads();
        __syncthreads();
    }
    __syncthreads();   // wrow ready; xs free for overlay

    // ---- phase 2: xnb = W @ x[b], 2-way j-split; partials into xs overlay ----
    float* part2 = xs;                    // [2][4][512] fp32 = 16 KB < 33 KB
    const int jq  = __builtin_amdgcn_readfirstlane(t >> 7);
    const int c4f = (t & 127) * 4;
    float4 a2[4];
    #pragma unroll
    for (int r = 0; r < 4; ++r) { a2[r].x = a2[r].y = a2[r].z = a2[r].w = 0.f; }

    #pragma unroll 4
    for (int jj = 0; jj < 64; ++jj) {
        const int jx = jq * 64 + jj;
        const float4 xj = *(const float4*)&xb[(size_t)jx * CHN + c4f];
        const float w0 = wrow[0][jx], w1 = wrow[1][jx];
        const float w2 = wrow[2][jx], w3 = wrow[3][jx];
        a2[0].x += w0 * xj.x; a2[0].y += w0 * xj.y; a2[0].z += w0 * xj.z; a2[0].w += w0 * xj.w;
        a2[1].x += w1 * xj.x; a2[1].y += w1 * xj.y; a2[1].z += w1 * xj.z; a2[1].w += w1 * xj.w;
        a2[2].x += w2 * xj.x; a2[2].y += w2 * xj.y; a2[2].z += w2 * xj.z; a2[2].w += w2 * xj.w;
        a2[3].x += w3 * xj.x; a2[3].y += w3 * xj.y; a2[3].z += w3 * xj.z; a2[3].w += w3 * xj.w;
    }
    #pragma unroll
    for (int r = 0; r < 4; ++r)
        *(float4*)&part2[(jq * 4 + r) * CHN + c4f] = a2[r];
    __syncthreads();

    // ---- reduce + bf16 write of [x | xnb]; thread owns (row, 8 channels) ----
    {
        const int row = t >> 6;              // 0..3
        const int cc  = (t & 63) * 8;        // 0..504
        float4 p0a = *(const float4*)&part2[(0 + row) * CHN + cc];
        float4 p1a = *(const float4*)&part2[(4 + row) * CHN + cc];
        float4 p0b = *(const float4*)&part2[(0 + row) * CHN + cc + 4];
        float4 p1b = *(const float4*)&part2[(4 + row) * CHN + cc + 4];
        const size_t rowg = (size_t)(b * NTOK + i0 + row);
        BfPack4 pa, pb;
        pa.h[0] = __float2bfloat16(p0a.x + p1a.x);
        pa.h[1] = __float2bfloat16(p0a.y + p1a.y);
        pa.h[2] = __float2bfloat16(p0a.z + p1a.z);
        pa.h[3] = __float2bfloat16(p0a.w + p1a.w);
        pb.h[0] = __float2bfloat16(p0b.x + p1b.x);
        pb.h[1] = __float2bfloat16(p0b.y + p1b.y);
        pb.h[2] = __float2bfloat16(p0b.z + p1b.z);
        pb.h[3] = __float2bfloat16(p0b.w + p1b.w);
        *(ushort4*)&hb[rowg * KTOT + CHN + cc]     = pa.u;
        *(ushort4*)&hb[rowg * KTOT + CHN + cc + 4] = pb.u;

        const float4 xv0 = *(const float4*)&xb[(size_t)(i0 + row) * CHN + cc];
        const float4 xv1 = *(const float4*)&xb[(size_t)(i0 + row) * CHN + cc + 4];
        pa.h[0] = __float2bfloat16(xv0.x); pa.h[1] = __float2bfloat16(xv0.y);
        pa.h[2] = __float2bfloat16(xv0.z); pa.h[3] = __float2bfloat16(xv0.w);
        pb.h[0] = __float2bfloat16(xv1.x); pb.h[1] = __float2bfloat16(xv1.y);
        pb.h[2] = __float2bfloat16(xv1.z); pb.h[3] = __float2bfloat16(xv1.w);
        *(ushort4*)&hb[rowg * KTOT + cc]     = pa.u;
        *(ushort4*)&hb[rowg * KTOT + cc + 4] = pb.u;
    }
}

// ---------------------------------------------------------------------------
// K2: out = relu(BN([x|xnb] @ Wf^T + bias)) via bf16 MFMA, direct global frags.
// UNCHANGED from round 1/2 (control).
// ---------------------------------------------------------------------------
__global__ __launch_bounds__(256)
void k2_gemm_bn_relu(const __hip_bfloat16* __restrict__ hbp,
                     const __hip_bfloat16* __restrict__ wfbp,
                     const float* __restrict__ fb,
                     const float* __restrict__ gg,
                     const float* __restrict__ bb,
                     const float* __restrict__ mm,
                     const float* __restrict__ vv,
                     float* __restrict__ out)
{
    const int blk  = blockIdx.x;
    const int r0   = (blk >> 3) << 6;
    const int c0   = (blk & 7) << 6;
    const int t    = threadIdx.x;
    const int w    = t >> 6;
    const int lane = t & 63;
    const int wm   = w & 1;
    const int wn   = w >> 1;
    const int m16  = lane & 15;
    const int qq   = lane >> 4;

    const short* A0 = (const short*)hbp  + (size_t)(r0 + wm * 32 + m16) * KTOT + qq * 8;
    const short* B0 = (const short*)wfbp + (size_t)(c0 + wn * 32 + m16) * KTOT + qq * 8;

    f32x4 acc00 = {0.f, 0.f, 0.f, 0.f};
    f32x4 acc01 = acc00, acc10 = acc00, acc11 = acc00;

    #pragma unroll 4
    for (int k0 = 0; k0 < KTOT; k0 += 32) {
        const bf16x8 aA = *(const bf16x8*)(A0 + k0);
        const bf16x8 aB = *(const bf16x8*)(A0 + 16 * KTOT + k0);
        const bf16x8 bA = *(const bf16x8*)(B0 + k0);
        const bf16x8 bB = *(const bf16x8*)(B0 + 16 * KTOT + k0);
        acc00 = __builtin_amdgcn_mfma_f32_16x16x32_bf16(aA, bA, acc00, 0, 0, 0);
        acc01 = __builtin_amdgcn_mfma_f32_16x16x32_bf16(aA, bB, acc01, 0, 0, 0);
        acc10 = __builtin_amdgcn_mfma_f32_16x16x32_bf16(aB, bA, acc10, 0, 0, 0);
        acc11 = __builtin_amdgcn_mfma_f32_16x16x32_bf16(aB, bB, acc11, 0, 0, 0);
    }

    // epilogue: C/D layout col = lane&15, row = (lane>>4)*4 + reg  [m89-verified]
    #pragma unroll
    for (int ni = 0; ni < 2; ++ni) {
        const int c = c0 + wn * 32 + ni * 16 + m16;
        const float gf = gg[c] * rsqrtf(vv[c] + EPSV);
        const float ad = fb[c] - mm[c];
        const float bv = bb[c];
        const f32x4 acr0 = ni ? acc01 : acc00;
        const f32x4 acr1 = ni ? acc11 : acc10;
        #pragma unroll
        for (int r2 = 0; r2 < 4; ++r2) {
            int row = r0 + wm * 32 + qq * 4 + r2;
            float val = (acr0[r2] + ad) * gf + bv;
            out[(size_t)row * CHN + c] = fmaxf(val, 0.f);
            row += 16;
            val = (acr1[r2] + ad) * gf + bv;
            out[(size_t)row * CHN + c] = fmaxf(val, 0.f);
        }
    }
}

extern "C" void kernel_launch(void* const* d_in, const int* in_sizes, int n_in,
                              void* d_out, int out_size, void* d_ws, size_t ws_size,
                              hipStream_t stream) {
    const float* x        = (const float*)d_in[0];
    // d_in[1] = y          : unused (softmax shift-invariance)
    const float* conv_e_w = (const float*)d_in[2];
    // d_in[3] = conv_e_b   : unused (shift)
    const float* bn_e_g   = (const float*)d_in[4];
    // d_in[5] = bn_e_b     : unused (shift)
    // d_in[6] = bn_e_m     : unused (shift)
    const float* bn_e_v   = (const float*)d_in[7];
    const float* conv_f_w = (const float*)d_in[8];
    const float* conv_f_b = (const float*)d_in[9];
    const float* bn_f_g   = (const float*)d_in[10];
    const float* bn_f_b   = (const float*)d_in[11];
    const float* bn_f_m   = (const float*)d_in[12];
    const float* bn_f_v   = (const float*)d_in[13];
    float* out = (float*)d_out;

    __hip_bfloat16* hb  = (__hip_bfloat16*)d_ws;              // 2048*1024 bf16 = 4 MB
    __hip_bfloat16* wfb = hb + (size_t)2048 * 1024;           // 512*1024 bf16  = 1 MB

    k1_score_softmax_xnb<<<512, 256, 0, stream>>>(x, conv_e_w, bn_e_g, bn_e_v,
                                                  conv_f_w, hb, wfb);
    k2_gemm_bn_relu<<<256, 256, 0, stream>>>(hb, wfb, conv_f_b, bn_f_g, bn_f_b,
                                             bn_f_m, bn_f_v, out);
}